// Round 9
// baseline (267.593 us; speedup 1.0000x reference)
//
#include <hip/hip_runtime.h>
#include <stdint.h>

#define F_IN   22000
#define B_SZ   4096
#define T_STEPS 100
#define NSPLIT 16
#define NCHUNK 22
#define KSPAN  (NCHUNK * 64)      // 1408; 16*1408 = 22528 >= 22000
#define ACC_STRIDE 104
#define ACCB_BYTES ((size_t)B_SZ * ACC_STRIDE * 4)       // 1,703,936
#define BIMG_BYTES 28672          // 7 ct * 4 frags * 64 lanes * 16B
#define W1IMG_BYTES ((size_t)NSPLIT * NCHUNK * BIMG_BYTES) // 10,092,544
#define WRIMG_BYTES (128 * 1024)

typedef float f32x4 __attribute__((ext_vector_type(4)));
typedef short s16x8 __attribute__((ext_vector_type(8)));

__device__ inline unsigned short f2bf(float f){
  unsigned u = __builtin_bit_cast(unsigned, f);
  u += 0x7FFFu + ((u >> 16) & 1u);          // round-to-nearest-even
  return (unsigned short)(u >> 16);
}
__device__ inline float bf2f(unsigned short h){
  return __builtin_bit_cast(float, ((unsigned)h) << 16);
}
__device__ inline float sigf(float x){
  return __builtin_amdgcn_rcpf(1.f + __expf(-x));
}
__device__ inline float tanhf_(float x){
  return 1.f - 2.f * __builtin_amdgcn_rcpf(__expf(2.f * x) + 1.f);
}

// ---------------- zero the dense accumulator ----------------
__global__ __launch_bounds__(256) void k_zero(float4* __restrict__ p, int n4){
  int i = blockIdx.x * 256 + threadIdx.x;
  if (i < n4) p[i] = make_float4(0.f, 0.f, 0.f, 0.f);
}

// ---- W1 [22000][100] f32 -> per-(split,chunk) FRAGMENT-ORDERED bf16 image ----
// frag layout: byte = chunkbase + (ct*4 + sub)*1024 + lane*16
//   sub: 0 = hi(k 0..31), 1 = lo(k 0..31), 2 = hi(k 32..63), 3 = lo(k 32..63)
//   lane fragment j (0..7): col = ct*16 + (lane&15), k = k0 + (sub>>1)*32 + (lane>>4)*8 + j
__global__ __launch_bounds__(256) void k_w1img(const float* __restrict__ W1,
                                               char* __restrict__ img){
  __shared__ float tile[64][129];
  int ch = blockIdx.x, s = blockIdx.y;
  int k0 = s * KSPAN + ch * 64;
  char* base = img + ((size_t)(s * NCHUNK + ch)) * BIMG_BYTES;
  int tid = threadIdx.x;
  for (int idx = tid; idx < 64 * 128; idx += 256){
    int k = idx >> 7, c = idx & 127;
    float v = 0.f;
    if (c < 100 && (k0 + k) < F_IN) v = W1[(size_t)(k0 + k) * 100 + c];
    tile[k][c] = v;
  }
  __syncthreads();
  #pragma unroll
  for (int q = 0; q < 7; ++q){
    int t = q * 256 + tid;              // 0..1791
    int lane = t & 63, frag = t >> 6;   // frag 0..27
    int ct = frag >> 2, sub = frag & 3;
    int half = sub >> 1, hilo = sub & 1;
    int c  = ct * 16 + (lane & 15);
    int kb = half * 32 + (lane >> 4) * 8;
    unsigned pk[4];
    #pragma unroll
    for (int jj = 0; jj < 4; ++jj){
      float v0 = tile[kb + jj * 2][c];
      float v1 = tile[kb + jj * 2 + 1][c];
      unsigned short h0 = f2bf(v0), l0 = f2bf(v0 - bf2f(h0));
      unsigned short h1 = f2bf(v1), l1 = f2bf(v1 - bf2f(h1));
      unsigned short e0 = hilo ? l0 : h0;
      unsigned short e1 = hilo ? l1 : h1;
      pk[jj] = (unsigned)e0 | ((unsigned)e1 << 16);
    }
    *(uint4*)(base + (size_t)t * 16) = make_uint4(pk[0], pk[1], pk[2], pk[3]);
  }
}

// ---- Wr [128][512] f32 -> fragment-ordered bf16 image (one-time, 128 KB) ----
__global__ __launch_bounds__(256) void k_wrimg(const float* __restrict__ Wr,
                                               char* __restrict__ wrimg){
  int gid = blockIdx.x * 256 + threadIdx.x;   // 0..8191
  int lane = gid & 63, slot = gid >> 6;
  int kk = slot & 3, G = (slot >> 2) & 3, w = slot >> 4;
  int oct = lane >> 4, lr = lane & 15;
  int col = G * 128 + w * 16 + lr;
  unsigned pk[4];
  #pragma unroll
  for (int jj = 0; jj < 4; ++jj){
    float v0 = Wr[(size_t)(kk * 32 + oct * 8 + jj * 2)     * 512 + col];
    float v1 = Wr[(size_t)(kk * 32 + oct * 8 + jj * 2 + 1) * 512 + col];
    pk[jj] = (unsigned)f2bf(v0) | ((unsigned)f2bf(v1) << 16);
  }
  *(uint4*)(wrimg + (size_t)gid * 16) = make_uint4(pk[0], pk[1], pk[2], pk[3]);
}

// ---- dense: M=128/block, NO LDS, NO barriers; A dbuf in regs, B frags reg-loaded from L2 ----
__global__ __launch_bounds__(256, 2) void k_dense(const float* __restrict__ x,
                                                  const char* __restrict__ img,
                                                  float* __restrict__ accb){
  int tid = threadIdx.x;
  int lane = tid & 63, w = tid >> 6;           // w in [0,4)
  int r = lane & 15, oct = lane >> 4;
  int brow = blockIdx.x * 128;
  int s = blockIdx.y;
  int arow0 = brow + w * 32 + r;
  const float* xrow0 = x + (size_t)arow0 * F_IN;
  const float* xrow1 = xrow0 + (size_t)16 * F_IN;
  const char* isrc = img + (size_t)s * NCHUNK * BIMG_BYTES + (size_t)lane * 16;
  int kbase = s * KSPAN;

  f32x4 acc0[7], acc1[7];
  #pragma unroll
  for (int i = 0; i < 7; ++i){ acc0[i] = (f32x4)0.f; acc1[i] = (f32x4)0.f; }

  float4 xa0, xa1, xa2, xa3, xb0, xb1, xb2, xb3;
  float4 ya0, ya1, ya2, ya3, yb0, yb1, yb2, yb3;

#define ALOAD(CH, A0, A1, A2, A3, B0, B1, B2, B3) do{                        \
    int k0_ = kbase + (CH) * 64;                                             \
    int ka0_ = k0_ + oct * 8;                                                \
    int ka1_ = k0_ + 32 + oct * 8;                                           \
    A0 = make_float4(0.f,0.f,0.f,0.f); A1 = A0; A2 = A0; A3 = A0;            \
    B0 = A0; B1 = A0; B2 = A0; B3 = A0;                                      \
    if (ka0_ < F_IN){ A0 = *(const float4*)(xrow0 + ka0_);                   \
                      A1 = *(const float4*)(xrow0 + ka0_ + 4);               \
                      B0 = *(const float4*)(xrow1 + ka0_);                   \
                      B1 = *(const float4*)(xrow1 + ka0_ + 4); }             \
    if (ka1_ < F_IN){ A2 = *(const float4*)(xrow0 + ka1_);                   \
                      A3 = *(const float4*)(xrow0 + ka1_ + 4);               \
                      B2 = *(const float4*)(xrow1 + ka1_);                   \
                      B3 = *(const float4*)(xrow1 + ka1_ + 4); }             \
  }while(0)

#define LDB(CH, CT, F0, F1, F2, F3) do{                                      \
    const char* b_ = isrc + (size_t)(CH) * BIMG_BYTES + (CT) * 4096;         \
    F0 = *(const s16x8*)(b_);                                                \
    F1 = *(const s16x8*)(b_ + 1024);                                         \
    F2 = *(const s16x8*)(b_ + 2048);                                         \
    F3 = *(const s16x8*)(b_ + 3072);                                         \
  }while(0)

#define CONV16(VA, H0, L0, H1, L1) do{                                       \
    _Pragma("unroll")                                                        \
    for (int j_ = 0; j_ < 8; ++j_){                                          \
      unsigned short h_ = f2bf(VA[j_]);                                      \
      H0[j_] = (short)h_; L0[j_] = (short)f2bf(VA[j_] - bf2f(h_));           \
    }                                                                        \
    _Pragma("unroll")                                                        \
    for (int j_ = 0; j_ < 8; ++j_){                                          \
      unsigned short h_ = f2bf(VA[8 + j_]);                                  \
      H1[j_] = (short)h_; L1[j_] = (short)f2bf(VA[8 + j_] - bf2f(h_));       \
    }                                                                        \
  }while(0)

  // 12 MFMAs for one ct using frags BH0/BL0 (k 0..31) and BH1/BL1 (k 32..63)
#define MFMA_CT(CT, BH0, BL0, BH1, BL1)                                      \
    acc0[CT] = __builtin_amdgcn_mfma_f32_16x16x32_bf16(pah0_, BH0, acc0[CT], 0, 0, 0); \
    acc0[CT] = __builtin_amdgcn_mfma_f32_16x16x32_bf16(pah0_, BL0, acc0[CT], 0, 0, 0); \
    acc0[CT] = __builtin_amdgcn_mfma_f32_16x16x32_bf16(pal0_, BH0, acc0[CT], 0, 0, 0); \
    acc0[CT] = __builtin_amdgcn_mfma_f32_16x16x32_bf16(pah1_, BH1, acc0[CT], 0, 0, 0); \
    acc0[CT] = __builtin_amdgcn_mfma_f32_16x16x32_bf16(pah1_, BL1, acc0[CT], 0, 0, 0); \
    acc0[CT] = __builtin_amdgcn_mfma_f32_16x16x32_bf16(pal1_, BH1, acc0[CT], 0, 0, 0); \
    acc1[CT] = __builtin_amdgcn_mfma_f32_16x16x32_bf16(qah0_, BH0, acc1[CT], 0, 0, 0); \
    acc1[CT] = __builtin_amdgcn_mfma_f32_16x16x32_bf16(qah0_, BL0, acc1[CT], 0, 0, 0); \
    acc1[CT] = __builtin_amdgcn_mfma_f32_16x16x32_bf16(qal0_, BH0, acc1[CT], 0, 0, 0); \
    acc1[CT] = __builtin_amdgcn_mfma_f32_16x16x32_bf16(qah1_, BH1, acc1[CT], 0, 0, 0); \
    acc1[CT] = __builtin_amdgcn_mfma_f32_16x16x32_bf16(qah1_, BL1, acc1[CT], 0, 0, 0); \
    acc1[CT] = __builtin_amdgcn_mfma_f32_16x16x32_bf16(qal1_, BH1, acc1[CT], 0, 0, 0);

#define COMPUTE(CH, A0, A1, A2, A3, B0, B1, B2, B3) do{                      \
    float va_[16] = {A0.x,A0.y,A0.z,A0.w, A1.x,A1.y,A1.z,A1.w,               \
                     A2.x,A2.y,A2.z,A2.w, A3.x,A3.y,A3.z,A3.w};              \
    float vb_[16] = {B0.x,B0.y,B0.z,B0.w, B1.x,B1.y,B1.z,B1.w,               \
                     B2.x,B2.y,B2.z,B2.w, B3.x,B3.y,B3.z,B3.w};              \
    s16x8 pah0_, pal0_, pah1_, pal1_, qah0_, qal0_, qah1_, qal1_;            \
    CONV16(va_, pah0_, pal0_, pah1_, pal1_);                                 \
    CONV16(vb_, qah0_, qal0_, qah1_, qal1_);                                 \
    s16x8 u0_, u1_, u2_, u3_, v0_, v1_, v2_, v3_;                            \
    LDB(CH, 0, u0_, u1_, u2_, u3_);                                          \
    LDB(CH, 1, v0_, v1_, v2_, v3_);  MFMA_CT(0, u0_, u1_, u2_, u3_);         \
    LDB(CH, 2, u0_, u1_, u2_, u3_);  MFMA_CT(1, v0_, v1_, v2_, v3_);         \
    LDB(CH, 3, v0_, v1_, v2_, v3_);  MFMA_CT(2, u0_, u1_, u2_, u3_);         \
    LDB(CH, 4, u0_, u1_, u2_, u3_);  MFMA_CT(3, v0_, v1_, v2_, v3_);         \
    LDB(CH, 5, v0_, v1_, v2_, v3_);  MFMA_CT(4, u0_, u1_, u2_, u3_);         \
    LDB(CH, 6, u0_, u1_, u2_, u3_);  MFMA_CT(5, v0_, v1_, v2_, v3_);         \
    MFMA_CT(6, u0_, u1_, u2_, u3_);                                          \
  }while(0)

  ALOAD(0, xa0, xa1, xa2, xa3, xb0, xb1, xb2, xb3);
  for (int ch = 0; ch < NCHUNK; ch += 2){
    if (ch + 1 < NCHUNK)
      ALOAD(ch + 1, ya0, ya1, ya2, ya3, yb0, yb1, yb2, yb3);
    COMPUTE(ch, xa0, xa1, xa2, xa3, xb0, xb1, xb2, xb3);
    if (ch + 2 < NCHUNK)
      ALOAD(ch + 2, xa0, xa1, xa2, xa3, xb0, xb1, xb2, xb3);
    if (ch + 1 < NCHUNK)
      COMPUTE(ch + 1, ya0, ya1, ya2, ya3, yb0, yb1, yb2, yb3);
  }

#undef ALOAD
#undef LDB
#undef CONV16
#undef MFMA_CT
#undef COMPUTE

  // ---- epilogue: C/D layout col=lane&15, row=oct*4+reg; two row-tiles ----
  #pragma unroll
  for (int ct = 0; ct < 7; ++ct){
    int col = ct * 16 + r;
    if (col < 100){
      #pragma unroll
      for (int reg = 0; reg < 4; ++reg){
        int orow0 = brow + w * 32 + oct * 4 + reg;
        atomicAdd(&accb[(size_t)orow0 * ACC_STRIDE + col], acc0[ct][reg]);
        atomicAdd(&accb[(size_t)(orow0 + 16) * ACC_STRIDE + col], acc1[ct][reg]);
      }
    }
  }
}

// ---------------- LSTM (512 thr / 8 waves, Wr from fragment image) + head ----------------
__global__ __launch_bounds__(512, 2) void k_lstm(const float* __restrict__ accb,
                                                 const float* __restrict__ b1,
                                                 const float* __restrict__ Wk,
                                                 const char* __restrict__ wrimg,
                                                 const float* __restrict__ bl,
                                                 const float* __restrict__ W2,
                                                 const float* __restrict__ b2,
                                                 float* __restrict__ out){
  __shared__ unsigned short hbuf[2][16 * 128]; // bf16 h, XOR-swizzled rows of 256B
  __shared__ float dld[16][ACC_STRIDE];
  __shared__ float hf[16][132];
  int tid = threadIdx.x;
  int lane = tid & 63, w = tid >> 6;           // w in [0,8)
  int oct = lane >> 4, lr = lane & 15;
  int brow = blockIdx.x * 16;

  for (int i = tid; i < 2048; i += 512) hbuf[0][i] = 0;
  for (int i = tid; i < 16 * T_STEPS; i += 512){
    int r = i / T_STEPS, t = i % T_STEPS;
    dld[r][t] = accb[(size_t)(brow + r) * ACC_STRIDE + t] + b1[t];
  }

  float wkv[4], blv[4];
  s16x8 bfrag[4][4];
  #pragma unroll
  for (int G = 0; G < 4; ++G){
    int col = G * 128 + w * 16 + lr;
    wkv[G] = Wk[col];
    blv[G] = bl[col];
    #pragma unroll
    for (int kk = 0; kk < 4; ++kk){
      bfrag[G][kk] = *(const s16x8*)(wrimg +
          ((size_t)(((w * 4 + G) * 4 + kk) * 64 + lane)) * 16);
    }
  }
  float cst[4];
  #pragma unroll
  for (int reg = 0; reg < 4; ++reg) cst[reg] = 0.f;
  __syncthreads();

  for (int t = 0; t < T_STEPS; ++t){
    int cur = t & 1;
    f32x4 acc[4];
    float dv[4];
    #pragma unroll
    for (int reg = 0; reg < 4; ++reg) dv[reg] = dld[oct * 4 + reg][t];
    #pragma unroll
    for (int G = 0; G < 4; ++G)
      #pragma unroll
      for (int reg = 0; reg < 4; ++reg)
        acc[G][reg] = dv[reg] * wkv[G] + blv[G];
    #pragma unroll
    for (int kk = 0; kk < 4; ++kk){
      int abyte = (lr * 256 + kk * 64 + oct * 16) ^ ((lr & 7) << 4);
      s16x8 a = *(s16x8*)((char*)hbuf[cur] + abyte);
      #pragma unroll
      for (int G = 0; G < 4; ++G)
        acc[G] = __builtin_amdgcn_mfma_f32_16x16x32_bf16(a, bfrag[G][kk], acc[G], 0, 0, 0);
    }
    #pragma unroll
    for (int reg = 0; reg < 4; ++reg){
      float iv = sigf(acc[0][reg]);
      float fv = sigf(acc[1][reg]);
      float gv = tanhf_(acc[2][reg]);
      float ov = sigf(acc[3][reg]);
      float cv = fv * cst[reg] + iv * gv;
      cst[reg] = cv;
      float hv = ov * tanhf_(cv);
      int row = oct * 4 + reg;
      int col = w * 16 + lr;
      int byte = (row * 256 + col * 2) ^ ((row & 7) << 4);
      *(unsigned short*)((char*)hbuf[cur ^ 1] + byte) = f2bf(hv);
      if (t == T_STEPS - 1) hf[row][col] = hv;
    }
    __syncthreads();
  }

  if (tid < 64){
    int row = tid >> 2, cl = tid & 3;
    float a = b2[cl];
    #pragma unroll 8
    for (int j = 0; j < 128; ++j) a += hf[row][j] * W2[j * 4 + cl];
    float m = fmaxf(a, __shfl_xor(a, 1));
    m = fmaxf(m, __shfl_xor(m, 2));
    float e = __expf(a - m);
    float se = e + __shfl_xor(e, 1);
    se += __shfl_xor(se, 2);
    out[(size_t)(brow + row) * 4 + cl] = e * __builtin_amdgcn_rcpf(se);
  }
}

extern "C" void kernel_launch(void* const* d_in, const int* in_sizes, int n_in,
                              void* d_out, int out_size, void* d_ws, size_t ws_size,
                              hipStream_t stream){
  const float* x  = (const float*)d_in[0];
  const float* W1 = (const float*)d_in[1];
  const float* b1 = (const float*)d_in[2];
  const float* Wk = (const float*)d_in[3];
  const float* Wr = (const float*)d_in[4];
  const float* bl = (const float*)d_in[5];
  const float* W2 = (const float*)d_in[6];
  const float* b2 = (const float*)d_in[7];
  float* out = (float*)d_out;

  // ws: accb f32[4096][104] | W1 fragment image | Wr fragment image
  float* accb  = (float*)d_ws;
  char*  img   = (char*)d_ws + ACCB_BYTES;
  char*  wrimg = (char*)d_ws + ACCB_BYTES + W1IMG_BYTES;
  const int n4 = B_SZ * ACC_STRIDE / 4;

  k_zero<<<(n4 + 255) / 256, 256, 0, stream>>>((float4*)accb, n4);
  k_w1img<<<dim3(NCHUNK, NSPLIT), 256, 0, stream>>>(W1, img);
  k_wrimg<<<32, 256, 0, stream>>>(Wr, wrimg);
  k_dense<<<dim3(B_SZ / 128, NSPLIT), 256, 0, stream>>>(x, img, accb);
  k_lstm<<<B_SZ / 16, 512, 0, stream>>>(accb, b1, Wk, wrimg, bl, W2, b2, out);
}

// Round 11
// 234.941 us; speedup vs baseline: 1.1390x; 1.1390x over previous
//
#include <hip/hip_runtime.h>
#include <stdint.h>

#define F_IN   22000
#define B_SZ   4096
#define T_STEPS 100
#define NSPLIT 16
#define NCHUNK 22
#define KSPAN  (NCHUNK * 64)      // 1408; 16*1408 = 22528 >= 22000
#define ACC_STRIDE 104
#define ACCB_BYTES ((size_t)B_SZ * ACC_STRIDE * 4)       // 1,703,936
#define BIMG_BYTES 28672          // 112 cols * 64 k * 2B * (hi+lo), XOR-swizzled rows
#define BIMG_HALF  14336
#define W1IMG_BYTES ((size_t)NSPLIT * NCHUNK * BIMG_BYTES) // 10,092,544

typedef float f32x4 __attribute__((ext_vector_type(4)));
typedef short s16x8 __attribute__((ext_vector_type(8)));

__device__ inline unsigned short f2bf(float f){
  unsigned u = __builtin_bit_cast(unsigned, f);
  u += 0x7FFFu + ((u >> 16) & 1u);          // round-to-nearest-even
  return (unsigned short)(u >> 16);
}
__device__ inline float bf2f(unsigned short h){
  return __builtin_bit_cast(float, ((unsigned)h) << 16);
}
__device__ inline float sigf(float x){
  return __builtin_amdgcn_rcpf(1.f + __expf(-x));
}
__device__ inline float tanhf_(float x){
  return 1.f - 2.f * __builtin_amdgcn_rcpf(__expf(2.f * x) + 1.f);
}

// ---------------- fused prep: zero accb | W1 swizzled image | Wr fragment image ----------------
// blocks [0,352): w1img  |  [352,384): wrimg  |  [384,488): zero accb
__global__ __launch_bounds__(256) void k_prep(const float* __restrict__ W1,
                                              const float* __restrict__ Wr,
                                              char* __restrict__ img,
                                              char* __restrict__ wrimg,
                                              float4* __restrict__ accb4){
  __shared__ float tile[64][129];
  int b = blockIdx.x, tid = threadIdx.x;
  if (b < 352){
    int ch = b % NCHUNK, s = b / NCHUNK;
    int k0 = s * KSPAN + ch * 64;
    char* base = img + ((size_t)(s * NCHUNK + ch)) * BIMG_BYTES;
    for (int idx = tid; idx < 64 * 128; idx += 256){
      int k = idx >> 7, c = idx & 127;
      float v = 0.f;
      if (c < 100 && (k0 + k) < F_IN) v = W1[(size_t)(k0 + k) * 100 + c];
      tile[k][c] = v;
    }
    __syncthreads();
    #pragma unroll
    for (int q = 0; q < 4; ++q){
      int task = q * 256 + tid;
      if (task < 896){
        int p  = task * 16;
        int c  = p >> 7;
        int k8 = ((p >> 4) & 7) ^ (c & 7);
        unsigned hw[4], lw[4];
        #pragma unroll
        for (int jj = 0; jj < 4; ++jj){
          float v0 = tile[k8 * 8 + jj * 2][c];
          float v1 = tile[k8 * 8 + jj * 2 + 1][c];
          unsigned short h0 = f2bf(v0), l0 = f2bf(v0 - bf2f(h0));
          unsigned short h1 = f2bf(v1), l1 = f2bf(v1 - bf2f(h1));
          hw[jj] = (unsigned)h0 | ((unsigned)h1 << 16);
          lw[jj] = (unsigned)l0 | ((unsigned)l1 << 16);
        }
        *(uint4*)(base + p)             = make_uint4(hw[0], hw[1], hw[2], hw[3]);
        *(uint4*)(base + BIMG_HALF + p) = make_uint4(lw[0], lw[1], lw[2], lw[3]);
      }
    }
  } else if (b < 384){
    int gid = (b - 352) * 256 + tid;          // 0..8191
    int lane = gid & 63, slot = gid >> 6;
    int kk = slot & 3, G = (slot >> 2) & 3, w = slot >> 4;
    int oct = lane >> 4, lr = lane & 15;
    int col = G * 128 + w * 16 + lr;
    unsigned pk[4];
    #pragma unroll
    for (int jj = 0; jj < 4; ++jj){
      float v0 = Wr[(size_t)(kk * 32 + oct * 8 + jj * 2)     * 512 + col];
      float v1 = Wr[(size_t)(kk * 32 + oct * 8 + jj * 2 + 1) * 512 + col];
      pk[jj] = (unsigned)f2bf(v0) | ((unsigned)f2bf(v1) << 16);
    }
    *(uint4*)(wrimg + (size_t)gid * 16) = make_uint4(pk[0], pk[1], pk[2], pk[3]);
  } else {
    int bb = b - 384;                          // 0..103, 1024 float4 each
    #pragma unroll
    for (int it = 0; it < 4; ++it)
      accb4[(size_t)bb * 1024 + it * 256 + tid] = make_float4(0.f, 0.f, 0.f, 0.f);
  }
}

// ---- dense: M=64/block, SINGLE 28KB LDS buffer, 4 blocks/CU; stage->sync->compute ----
__global__ __launch_bounds__(256, 4) void k_dense(const float* __restrict__ x,
                                                  const char* __restrict__ img,
                                                  float* __restrict__ accb){
  __shared__ char Bb[BIMG_BYTES];
  int tid = threadIdx.x;
  int lane = tid & 63, w = tid >> 6;           // w in [0,4)
  int r = lane & 15, oct = lane >> 4;
  int brow = blockIdx.x * 64;
  int s = blockIdx.y;
  int arow = brow + w * 16 + r;
  const float* xrow = x + (size_t)arow * F_IN;
  const char* isrc = img + (size_t)s * NCHUNK * BIMG_BYTES;
  int kbase = s * KSPAN;

  f32x4 acc[7];
  #pragma unroll
  for (int i = 0; i < 7; ++i) acc[i] = (f32x4)0.f;

  for (int ch = 0; ch < NCHUNK; ++ch){
    int k0 = kbase + ch * 64;
    // A loads issued first (HBM latency clock starts before stage)
    int ka0 = k0 + oct * 8;
    int ka1 = k0 + 32 + oct * 8;
    float4 a0 = make_float4(0.f,0.f,0.f,0.f), a1 = a0, a2 = a0, a3 = a0;
    if (ka0 < F_IN){ a0 = *(const float4*)(xrow + ka0);
                     a1 = *(const float4*)(xrow + ka0 + 4); }
    if (ka1 < F_IN){ a2 = *(const float4*)(xrow + ka1);
                     a3 = *(const float4*)(xrow + ka1 + 4); }
    // B stage: 7 x 1KB segments via global_load_lds
    {
      const char* src = isrc + (size_t)ch * BIMG_BYTES;
      #pragma unroll
      for (int i = 0; i < 7; ++i){
        int seg = i * 4 + w;
        __builtin_amdgcn_global_load_lds(
          (const __attribute__((address_space(1))) void*)(src + seg * 1024 + lane * 16),
          (__attribute__((address_space(3))) void*)(Bb + seg * 1024), 16, 0, 0);
      }
    }
    __syncthreads();   // drains loads; Bb coherent
    // convert A to hi/lo bf16 fragments
    float va[16] = {a0.x,a0.y,a0.z,a0.w, a1.x,a1.y,a1.z,a1.w,
                    a2.x,a2.y,a2.z,a2.w, a3.x,a3.y,a3.z,a3.w};
    s16x8 ah0, al0, ah1, al1;
    #pragma unroll
    for (int j = 0; j < 8; ++j){
      unsigned short h = f2bf(va[j]);
      ah0[j] = (short)h; al0[j] = (short)f2bf(va[j] - bf2f(h));
    }
    #pragma unroll
    for (int j = 0; j < 8; ++j){
      unsigned short h = f2bf(va[8 + j]);
      ah1[j] = (short)h; al1[j] = (short)f2bf(va[8 + j] - bf2f(h));
    }
    // MFMA over 7 col-tiles, split-precision 3-term per K-half
    #pragma unroll
    for (int ct = 0; ct < 7; ++ct){
      int c = ct * 16 + r;
      int byte0 = ((c * 128 + oct * 16) ^ ((c & 7) << 4));
      int byte1 = ((c * 128 + 64 + oct * 16) ^ ((c & 7) << 4));
      s16x8 bh0 = *(s16x8*)(Bb + byte0);
      s16x8 bl0 = *(s16x8*)(Bb + BIMG_HALF + byte0);
      s16x8 bh1 = *(s16x8*)(Bb + byte1);
      s16x8 bl1 = *(s16x8*)(Bb + BIMG_HALF + byte1);
      acc[ct] = __builtin_amdgcn_mfma_f32_16x16x32_bf16(ah0, bh0, acc[ct], 0, 0, 0);
      acc[ct] = __builtin_amdgcn_mfma_f32_16x16x32_bf16(ah0, bl0, acc[ct], 0, 0, 0);
      acc[ct] = __builtin_amdgcn_mfma_f32_16x16x32_bf16(al0, bh0, acc[ct], 0, 0, 0);
      acc[ct] = __builtin_amdgcn_mfma_f32_16x16x32_bf16(ah1, bh1, acc[ct], 0, 0, 0);
      acc[ct] = __builtin_amdgcn_mfma_f32_16x16x32_bf16(ah1, bl1, acc[ct], 0, 0, 0);
      acc[ct] = __builtin_amdgcn_mfma_f32_16x16x32_bf16(al1, bh1, acc[ct], 0, 0, 0);
    }
    __syncthreads();   // all reads done before next stage overwrites
  }

  // ---- epilogue: C/D layout col=lane&15, row=oct*4+reg ----
  #pragma unroll
  for (int ct = 0; ct < 7; ++ct){
    int col = ct * 16 + r;
    if (col < 100){
      #pragma unroll
      for (int reg = 0; reg < 4; ++reg){
        int orow = brow + w * 16 + oct * 4 + reg;
        atomicAdd(&accb[(size_t)orow * ACC_STRIDE + col], acc[ct][reg]);
      }
    }
  }
}

// ---------------- LSTM (512 thr / 8 waves, Wr from fragment image) + head ----------------
__global__ __launch_bounds__(512, 2) void k_lstm(const float* __restrict__ accb,
                                                 const float* __restrict__ b1,
                                                 const float* __restrict__ Wk,
                                                 const char* __restrict__ wrimg,
                                                 const float* __restrict__ bl,
                                                 const float* __restrict__ W2,
                                                 const float* __restrict__ b2,
                                                 float* __restrict__ out){
  __shared__ unsigned short hbuf[2][16 * 128]; // bf16 h, XOR-swizzled rows of 256B
  __shared__ float dld[16][ACC_STRIDE];
  __shared__ float hf[16][132];
  int tid = threadIdx.x;
  int lane = tid & 63, w = tid >> 6;           // w in [0,8)
  int oct = lane >> 4, lr = lane & 15;
  int brow = blockIdx.x * 16;

  for (int i = tid; i < 2048; i += 512) hbuf[0][i] = 0;
  for (int i = tid; i < 16 * T_STEPS; i += 512){
    int r = i / T_STEPS, t = i % T_STEPS;
    dld[r][t] = accb[(size_t)(brow + r) * ACC_STRIDE + t] + b1[t];
  }

  float wkv[4], blv[4];
  s16x8 bfrag[4][4];
  #pragma unroll
  for (int G = 0; G < 4; ++G){
    int col = G * 128 + w * 16 + lr;
    wkv[G] = Wk[col];
    blv[G] = bl[col];
    #pragma unroll
    for (int kk = 0; kk < 4; ++kk){
      bfrag[G][kk] = *(const s16x8*)(wrimg +
          ((size_t)(((w * 4 + G) * 4 + kk) * 64 + lane)) * 16);
    }
  }
  float cst[4];
  #pragma unroll
  for (int reg = 0; reg < 4; ++reg) cst[reg] = 0.f;
  __syncthreads();

  for (int t = 0; t < T_STEPS; ++t){
    int cur = t & 1;
    f32x4 acc[4];
    float dv[4];
    #pragma unroll
    for (int reg = 0; reg < 4; ++reg) dv[reg] = dld[oct * 4 + reg][t];
    #pragma unroll
    for (int G = 0; G < 4; ++G)
      #pragma unroll
      for (int reg = 0; reg < 4; ++reg)
        acc[G][reg] = dv[reg] * wkv[G] + blv[G];
    #pragma unroll
    for (int kk = 0; kk < 4; ++kk){
      int abyte = (lr * 256 + kk * 64 + oct * 16) ^ ((lr & 7) << 4);
      s16x8 a = *(s16x8*)((char*)hbuf[cur] + abyte);
      #pragma unroll
      for (int G = 0; G < 4; ++G)
        acc[G] = __builtin_amdgcn_mfma_f32_16x16x32_bf16(a, bfrag[G][kk], acc[G], 0, 0, 0);
    }
    #pragma unroll
    for (int reg = 0; reg < 4; ++reg){
      float iv = sigf(acc[0][reg]);
      float fv = sigf(acc[1][reg]);
      float gv = tanhf_(acc[2][reg]);
      float ov = sigf(acc[3][reg]);
      float cv = fv * cst[reg] + iv * gv;
      cst[reg] = cv;
      float hv = ov * tanhf_(cv);
      int row = oct * 4 + reg;
      int col = w * 16 + lr;
      int byte = (row * 256 + col * 2) ^ ((row & 7) << 4);
      *(unsigned short*)((char*)hbuf[cur ^ 1] + byte) = f2bf(hv);
      if (t == T_STEPS - 1) hf[row][col] = hv;
    }
    __syncthreads();
  }

  if (tid < 64){
    int row = tid >> 2, cl = tid & 3;
    float a = b2[cl];
    #pragma unroll 8
    for (int j = 0; j < 128; ++j) a += hf[row][j] * W2[j * 4 + cl];
    float m = fmaxf(a, __shfl_xor(a, 1));
    m = fmaxf(m, __shfl_xor(m, 2));
    float e = __expf(a - m);
    float se = e + __shfl_xor(e, 1);
    se += __shfl_xor(se, 2);
    out[(size_t)(brow + row) * 4 + cl] = e * __builtin_amdgcn_rcpf(se);
  }
}

extern "C" void kernel_launch(void* const* d_in, const int* in_sizes, int n_in,
                              void* d_out, int out_size, void* d_ws, size_t ws_size,
                              hipStream_t stream){
  const float* x  = (const float*)d_in[0];
  const float* W1 = (const float*)d_in[1];
  const float* b1 = (const float*)d_in[2];
  const float* Wk = (const float*)d_in[3];
  const float* Wr = (const float*)d_in[4];
  const float* bl = (const float*)d_in[5];
  const float* W2 = (const float*)d_in[6];
  const float* b2 = (const float*)d_in[7];
  float* out = (float*)d_out;

  // ws: accb f32[4096][104] | W1 swizzled image | Wr fragment image
  float* accb  = (float*)d_ws;
  char*  img   = (char*)d_ws + ACCB_BYTES;
  char*  wrimg = (char*)d_ws + ACCB_BYTES + W1IMG_BYTES;

  k_prep<<<488, 256, 0, stream>>>(W1, Wr, img, wrimg, (float4*)accb);
  k_dense<<<dim3(B_SZ / 64, NSPLIT), 256, 0, stream>>>(x, img, accb);
  k_lstm<<<B_SZ / 16, 512, 0, stream>>>(accb, b1, Wk, wrimg, bl, W2, b2, out);
}